// Round 7
// baseline (866.672 us; speedup 1.0000x reference)
//
#include <hip/hip_runtime.h>
#include <cmath>

// Problem constants: V=50000, E=300, H=512, L=6, N=8192, K=4
#define VSZ  50000
#define EDIM 300
#define EPAD 320      // E padded to multiple of 64
#define HDIM 512
#define LVLS 6
#define NN   8192
#define KCH  4

// MFMA GEMM tile: 128x128 block, BK=64, 4 waves of 64x64 (4x4 grid of 16x16x32 MFMA)
#define BM 128
#define BN 128
#define BKE 64

typedef __attribute__((ext_vector_type(8))) short bf16x8;
typedef __attribute__((ext_vector_type(8))) unsigned short us8;
typedef __attribute__((ext_vector_type(4))) float f32x4;

__device__ __forceinline__ float sigf(float x) { return 1.0f / (1.0f + expf(-x)); }

__device__ __forceinline__ unsigned short f2bf(float f) {
    unsigned u = __float_as_uint(f);
    u += 0x7FFF + ((u >> 16) & 1);           // RNE
    return (unsigned short)(u >> 16);
}
__device__ __forceinline__ float bf2f(unsigned short h) {
    return __uint_as_float(((unsigned)h) << 16);
}

// ---- transpose+convert weights: out[n][k] = bf16(in[k][n]), zero for k>=Kreal ----
__global__ __launch_bounds__(256) void wconv_k(
    const float* __restrict__ in, unsigned short* __restrict__ out,
    int Kreal, int Ksp, int Nd)
{
    int t = blockIdx.x * 256 + threadIdx.x;   // Nd*Ksp total, k fast
    int k = t % Ksp;
    int n = t / Ksp;
    out[t] = (k < Kreal) ? f2bf(in[(size_t)k * Nd + n]) : (unsigned short)0;
}

// AF32: 1 = A rows gathered from fp32 source (aidx), converted in-register,
//           ds_write_b128 into LDS (no bf16 copy of embed materialized).
//       0 = A rows dense bf16, staged via global_load_lds.
// EPI : 0 = C = bf16(acc)
//       1 = C = bf16(acc*rowscale[row] + (col<1536 ? b_iou[col] : b_f[col-1536]))
// Grid: blockIdx.x = M-tile, blockIdx.y = N-group; gridDim.x % 8 == 0 puts all
// N-groups of one M-tile on one XCD (round-robin), so shared-A re-reads stay
// L2-local (R6: FETCH 247->31 MB from this).
// BK=64 LDS layout: 16 B granules; chunk c (row=c>>3, slot=c&7) holds K-granule
// kg = slot ^ (row&7). Identity chunk placement -> wave-uniform DMA dest.
// Epilogue: acc -> bf16 via LDS (XOR swizzle), 128 B/thread contiguous stores.
// NOTE: no waves/EU clamp — acc needs 64 AGPRs; a (256,4) bound caps the unified
// VGPR+AGPR file at 128/wave and spills (R5: +280 MB scratch traffic).
template <int AF32, int EPI, int NCHUNK>
__global__ __launch_bounds__(256) void mgemm_k(
    const unsigned short* __restrict__ Ab,   // bf16 A (AF32=0)
    const float* __restrict__ Af,            // f32 A (AF32=1)
    const int* __restrict__ aidx, const float* __restrict__ rowscale,
    const unsigned short* __restrict__ Bt,
    const float* __restrict__ b_iou, const float* __restrict__ b_f,
    unsigned short* __restrict__ C, int ldc, int Ks, int KA)
{
    __shared__ __align__(16) unsigned short smem[2 * BM * BKE];  // 32 KB
    unsigned short* As = smem;               // [BM*BKE]
    unsigned short* Bs = smem + BM * BKE;    // [BN*BKE]

    const int tid  = threadIdx.x;
    const int wave = tid >> 6;
    const int lane = tid & 63;
    const int quad = lane >> 4;
    const int mcol = lane & 15;
    const int wm   = (wave >> 1) * 64;
    const int wn   = (wave & 1) * 64;
    const int tile_m = blockIdx.x * BM;

    // staging: 4 chunks per thread per matrix; chunk c_j = tid + 256*j
    int arow[4]; int kgo[4];
#pragma unroll
    for (int j = 0; j < 4; ++j) {
        int c   = tid + 256 * j;
        int row = c >> 3;
        kgo[j]  = ((c & 7) ^ (row & 7)) * 8;   // element offset within BK window
        arow[j] = row;
    }
    int agrow[4];
#pragma unroll
    for (int j = 0; j < 4; ++j)
        agrow[j] = AF32 ? aidx[tile_m + arow[j]] : (tile_m + arow[j]);

    for (int nc = 0; nc < NCHUNK; ++nc) {
        const int tile_n = (blockIdx.y * NCHUNK + nc) * BN;
        const unsigned short* bsrc[4];
#pragma unroll
        for (int j = 0; j < 4; ++j)
            bsrc[j] = Bt + (size_t)(tile_n + arow[j]) * Ks + kgo[j];

        f32x4 acc[4][4] = {};

        for (int k0 = 0; k0 < Ks; k0 += BKE) {
            // ---- stage A ----
            if (AF32) {
#pragma unroll
                for (int j = 0; j < 4; ++j) {
                    const int e = k0 + kgo[j];
                    float4 lo = make_float4(0.f, 0.f, 0.f, 0.f);
                    float4 hi = make_float4(0.f, 0.f, 0.f, 0.f);
                    const float* s = Af + (size_t)agrow[j] * KA + e;
                    if (e + 4 <= KA) lo = *(const float4*)s;
                    if (e + 8 <= KA) hi = *(const float4*)(s + 4);
                    us8 o;
                    o[0] = f2bf(lo.x); o[1] = f2bf(lo.y); o[2] = f2bf(lo.z); o[3] = f2bf(lo.w);
                    o[4] = f2bf(hi.x); o[5] = f2bf(hi.y); o[6] = f2bf(hi.z); o[7] = f2bf(hi.w);
                    *(us8*)(As + (size_t)(tid + 256 * j) * 8) = o;
                }
            } else {
#pragma unroll
                for (int j = 0; j < 4; ++j) {
                    __attribute__((address_space(3))) unsigned int* dA =
                        (__attribute__((address_space(3))) unsigned int*)(As + (wave * 64 + 256 * j) * 8);
                    __builtin_amdgcn_global_load_lds(
                        (const __attribute__((address_space(1))) unsigned int*)
                            (Ab + (size_t)agrow[j] * Ks + kgo[j] + k0), dA, 16, 0, 0);
                }
            }
            // ---- stage B (always bf16 DMA) ----
#pragma unroll
            for (int j = 0; j < 4; ++j) {
                __attribute__((address_space(3))) unsigned int* dB =
                    (__attribute__((address_space(3))) unsigned int*)(Bs + (wave * 64 + 256 * j) * 8);
                __builtin_amdgcn_global_load_lds(
                    (const __attribute__((address_space(1))) unsigned int*)(bsrc[j] + k0), dB, 16, 0, 0);
            }
            __syncthreads();

#pragma unroll
            for (int kh = 0; kh < 2; ++kh) {
                bf16x8 afr[4], bfr[4];
#pragma unroll
                for (int mt = 0; mt < 4; ++mt) {
                    int rw = wm + mt * 16 + mcol;
                    int p  = (kh * 4 + quad) ^ (rw & 7);
                    afr[mt] = *(const bf16x8*)(As + (rw * 8 + p) * 8);
                }
#pragma unroll
                for (int nt = 0; nt < 4; ++nt) {
                    int rw = wn + nt * 16 + mcol;
                    int p  = (kh * 4 + quad) ^ (rw & 7);
                    bfr[nt] = *(const bf16x8*)(Bs + (rw * 8 + p) * 8);
                }
#pragma unroll
                for (int mt = 0; mt < 4; ++mt)
#pragma unroll
                    for (int nt = 0; nt < 4; ++nt)
                        acc[mt][nt] = __builtin_amdgcn_mfma_f32_16x16x32_bf16(
                            afr[mt], bfr[nt], acc[mt][nt], 0, 0, 0);
            }
            __syncthreads();
        }

        // ---- epilogue: bf16 C-tile via LDS (XOR swizzle), contiguous stores ----
        unsigned short* Ct = smem;   // 32 KB = 128*128 ushort
#pragma unroll
        for (int mt = 0; mt < 4; ++mt) {
            const int rl = wm + mt * 16 + quad * 4;
            float4 ts = make_float4(1.f, 1.f, 1.f, 1.f);
            if (EPI == 1) ts = *(const float4*)&rowscale[tile_m + rl];
            const float tsv[4] = {ts.x, ts.y, ts.z, ts.w};
#pragma unroll
            for (int nt = 0; nt < 4; ++nt) {
                const int cl = wn + nt * 16 + mcol;
                float bv = 0.0f;
                if (EPI == 1) {
                    int col = tile_n + cl;
                    bv = (col < 3 * HDIM) ? b_iou[col] : b_f[col - 3 * HDIM];
                }
#pragma unroll
                for (int r = 0; r < 4; ++r) {
                    int row = rl + r;
                    int g   = (cl >> 3) ^ (row & 7);
                    float v = acc[mt][nt][r];
                    if (EPI == 1) v = v * tsv[r] + bv;
                    Ct[row * BN + g * 8 + (cl & 7)] = f2bf(v);
                }
            }
        }
        __syncthreads();
        {
            const int row  = tid >> 1;
            const int half = tid & 1;
            unsigned short* gp = C + (size_t)(tile_m + row) * ldc + tile_n + half * 64;
#pragma unroll
            for (int v = 0; v < 8; ++v) {
                int g  = half * 8 + v;
                int gs = g ^ (row & 7);
                *(us8*)(gp + v * 8) = *(const us8*)(Ct + row * BN + gs * 8);
            }
        }
        __syncthreads();   // LDS reused for staging next nc chunk
    }
}

// fused child-sum + fc + gates (non-leaf).
// ioux row: bf16 [i|o|u|xwf+bf] (2048). Z row: bf16 [h@U_iou (1536) | h@U_f (512)].
//   ia = i + sum_k m_k * Zi[c_k] ; fc = sum_k sigf(xw + m_k*Zf[c_k]) * m_k * c_prev[c_k]
//   c = sigf(ia)*tanh(ua) + fc ; h = sigf(oa)*tanh(c)
template <bool LAST>
__global__ __launch_bounds__(256) void gatefc_k(
    const unsigned short* __restrict__ ioux, const unsigned short* __restrict__ Z,
    const int* __restrict__ cidx, const float* __restrict__ cmask,
    const float* __restrict__ c_prev,
    float* __restrict__ c_new, unsigned short* __restrict__ hb_new,
    float* __restrict__ h_out)
{
    int t  = blockIdx.x * 256 + threadIdx.x;   // NN*HDIM/8 threads
    int n  = t >> 6;
    int j8 = (t & 63) << 3;
    const unsigned short* xr = ioux + (size_t)n * 4 * HDIM + j8;
    us8 xi = *(const us8*)xr;
    us8 xo = *(const us8*)(xr + HDIM);
    us8 xu = *(const us8*)(xr + 2 * HDIM);
    us8 xf = *(const us8*)(xr + 3 * HDIM);
    float ia[8], oa[8], ua[8], xw[8], fc[8];
#pragma unroll
    for (int j = 0; j < 8; ++j) {
        ia[j] = bf2f(xi[j]); oa[j] = bf2f(xo[j]);
        ua[j] = bf2f(xu[j]); xw[j] = bf2f(xf[j]);
        fc[j] = 0.0f;
    }
    int4   ci = *(const int4*)&cidx[n * KCH];
    float4 cm = *(const float4*)&cmask[n * KCH];
    const int   cia[4] = {ci.x, ci.y, ci.z, ci.w};
    const float cma[4] = {cm.x, cm.y, cm.z, cm.w};
#pragma unroll
    for (int k = 0; k < KCH; ++k) {
        const float m = cma[k];
        const unsigned short* zr = Z + (size_t)cia[k] * 4 * HDIM + j8;
        us8 zi = *(const us8*)zr;
        us8 zo = *(const us8*)(zr + HDIM);
        us8 zu = *(const us8*)(zr + 2 * HDIM);
        us8 zf = *(const us8*)(zr + 3 * HDIM);
        const float* cpr = c_prev + (size_t)cia[k] * HDIM + j8;
        float4 ca = *(const float4*)cpr;
        float4 cb = *(const float4*)(cpr + 4);
        const float cp[8] = {ca.x, ca.y, ca.z, ca.w, cb.x, cb.y, cb.z, cb.w};
#pragma unroll
        for (int j = 0; j < 8; ++j) {
            ia[j] += m * bf2f(zi[j]);
            oa[j] += m * bf2f(zo[j]);
            ua[j] += m * bf2f(zu[j]);
            fc[j] += sigf(xw[j] + m * bf2f(zf[j])) * m * cp[j];
        }
    }
    float cv[8], hv[8];
#pragma unroll
    for (int j = 0; j < 8; ++j) {
        cv[j] = sigf(ia[j]) * tanhf(ua[j]) + fc[j];
        hv[j] = sigf(oa[j]) * tanhf(cv[j]);
    }
    if (LAST) {
        *(float4*)(h_out + (size_t)n * HDIM + j8)     = make_float4(hv[0], hv[1], hv[2], hv[3]);
        *(float4*)(h_out + (size_t)n * HDIM + j8 + 4) = make_float4(hv[4], hv[5], hv[6], hv[7]);
    } else {
        *(float4*)(c_new + (size_t)n * HDIM + j8)     = make_float4(cv[0], cv[1], cv[2], cv[3]);
        *(float4*)(c_new + (size_t)n * HDIM + j8 + 4) = make_float4(cv[4], cv[5], cv[6], cv[7]);
        us8 hb;
#pragma unroll
        for (int j = 0; j < 8; ++j) hb[j] = f2bf(hv[j]);
        *(us8*)(hb_new + (size_t)n * HDIM + j8) = hb;
    }
}

// leaf: fc = 0, no children (reads only i|o|u cols of ioux)
__global__ __launch_bounds__(256) void gateleaf_k(
    const unsigned short* __restrict__ ioux,
    float* __restrict__ c_new, unsigned short* __restrict__ hb_new)
{
    int t  = blockIdx.x * 256 + threadIdx.x;
    int n  = t >> 6;
    int j8 = (t & 63) << 3;
    const unsigned short* xr = ioux + (size_t)n * 4 * HDIM + j8;
    us8 xi = *(const us8*)xr;
    us8 xo = *(const us8*)(xr + HDIM);
    us8 xu = *(const us8*)(xr + 2 * HDIM);
    float cv[8], hv[8];
#pragma unroll
    for (int j = 0; j < 8; ++j) {
        cv[j] = sigf(bf2f(xi[j])) * tanhf(bf2f(xu[j]));
        hv[j] = sigf(bf2f(xo[j])) * tanhf(cv[j]);
    }
    *(float4*)(c_new + (size_t)n * HDIM + j8)     = make_float4(cv[0], cv[1], cv[2], cv[3]);
    *(float4*)(c_new + (size_t)n * HDIM + j8 + 4) = make_float4(cv[4], cv[5], cv[6], cv[7]);
    us8 hb;
#pragma unroll
    for (int j = 0; j < 8; ++j) hb[j] = f2bf(hv[j]);
    *(us8*)(hb_new + (size_t)n * HDIM + j8) = hb;
}

extern "C" void kernel_launch(void* const* d_in, const int* in_sizes, int n_in,
                              void* d_out, int out_size, void* d_ws, size_t ws_size,
                              hipStream_t stream)
{
    const int*   vocab_ix   = (const int*)d_in[0];     // [L,N]
    const int*   child_idx  = (const int*)d_in[1];     // [L,N,K]
    const float* token_mask = (const float*)d_in[2];   // [L,N]
    const float* child_mask = (const float*)d_in[3];   // [L,N,K]
    const float* embed      = (const float*)d_in[4];   // [V,E] f32
    const float* W_iou      = (const float*)d_in[5];   // [E,3H]
    const float* U_iou      = (const float*)d_in[6];   // [H,3H]
    const float* b_iou      = (const float*)d_in[7];   // [3H]
    const float* W_f        = (const float*)d_in[8];   // [E,H]
    const float* U_f        = (const float*)d_in[9];   // [H,H]
    const float* b_f        = (const float*)d_in[10];  // [H]
    float* out = (float*)d_out;                        // [N,H] level-0 h

    // ---- workspace layout (~121 MB live < 256 MB L3: intermediates stay cached) ----
    float* ws = (float*)d_ws;
    float* c0 = ws;                                    // [N,H] f32
    float* c1 = c0 + (size_t)NN * HDIM;                // [N,H] f32
    unsigned short* usb   = (unsigned short*)(c1 + (size_t)NN * HDIM);
    unsigned short* hb0   = usb;                                // [N,H] bf16
    unsigned short* hb1   = hb0 + (size_t)NN * HDIM;            // [N,H] bf16
    unsigned short* ioux  = hb1 + (size_t)NN * HDIM;            // [N,4H] bf16 (reused per level)
    unsigned short* Z     = ioux + (size_t)NN * 4 * HDIM;       // [N,4H] bf16 (reused per level)
    unsigned short* WtALL = Z + (size_t)NN * 4 * HDIM;          // [4H,EPAD] bf16: W_iou^T|W_f^T
    unsigned short* UtALL = WtALL + (size_t)4 * HDIM * EPAD;    // [4H,H] bf16: U_iou^T|U_f^T

    dim3 blk(256);

    // ---- weight converts (7 MB total; every launch, ws is re-poisoned) ----
    wconv_k<<<dim3(3 * HDIM * EPAD / 256), blk, 0, stream>>>(W_iou, WtALL, EDIM, EPAD, 3 * HDIM);
    wconv_k<<<dim3(HDIM * EPAD / 256),     blk, 0, stream>>>(W_f, WtALL + (size_t)3 * HDIM * EPAD, EDIM, EPAD, HDIM);
    wconv_k<<<dim3(3 * HDIM * HDIM / 256), blk, 0, stream>>>(U_iou, UtALL, HDIM, HDIM, 3 * HDIM);
    wconv_k<<<dim3(HDIM * HDIM / 256),     blk, 0, stream>>>(U_f, UtALL + (size_t)3 * HDIM * HDIM, HDIM, HDIM, HDIM);

    unsigned short* bbuf[2] = { hb0, hb1 };
    float*          cbuf[2] = { c0,  c1  };

    const int ew_blocks = NN * HDIM / 8 / 256;   // 2048

    for (int l = LVLS - 1; l >= 0; --l) {
        const int p = (LVLS - 1 - l);
        unsigned short* hb_new  = bbuf[p & 1];
        float*          c_new   = cbuf[p & 1];
        unsigned short* hb_prev = bbuf[(p & 1) ^ 1];
        float*          c_prev  = cbuf[(p & 1) ^ 1];
        const int*   cix = child_idx  + (size_t)l * NN * KCH;
        const float* cm  = child_mask + (size_t)l * NN * KCH;
        const bool leaf = (l == LVLS - 1);

        // ioux = (embed[vix]*tm) @ [W_iou|W_f] + bias   [8192 x 320 x 2048]
        // fp32 A gathered+converted in-flight; leaf needs only iou (12 N-tiles).
        mgemm_k<1, 1, 2><<<dim3(NN / BM, leaf ? 6 : 8), blk, 0, stream>>>(
            nullptr, embed, vocab_ix + (size_t)l * NN, token_mask + (size_t)l * NN,
            WtALL, b_iou, b_f, ioux, 4 * HDIM, EPAD, EDIM);

        if (leaf) {
            gateleaf_k<<<dim3(ew_blocks), blk, 0, stream>>>(ioux, c_new, hb_new);
        } else {
            // Z = h_prev @ [U_iou | U_f]   [8192 x 512 x 2048]
            mgemm_k<0, 0, 2><<<dim3(NN / BM, 8), blk, 0, stream>>>(
                hb_prev, nullptr, nullptr, nullptr,
                UtALL, nullptr, nullptr, Z, 4 * HDIM, HDIM, HDIM);

            if (l == 0) {
                gatefc_k<true><<<dim3(ew_blocks), blk, 0, stream>>>(
                    ioux, Z, cix, cm, c_prev, nullptr, nullptr, out);
            } else {
                gatefc_k<false><<<dim3(ew_blocks), blk, 0, stream>>>(
                    ioux, Z, cix, cm, c_prev, c_new, hb_new, nullptr);
            }
        }
    }
}

// Round 8
// 713.939 us; speedup vs baseline: 1.2139x; 1.2139x over previous
//
#include <hip/hip_runtime.h>
#include <cmath>

// Problem constants: V=50000, E=300, H=512, L=6, N=8192, K=4
#define VSZ  50000
#define EDIM 300
#define EPAD 320      // E padded to multiple of 64
#define HDIM 512
#define LVLS 6
#define NN   8192
#define KCH  4

// MFMA GEMM: 128x128 block, BK=64, 4 waves of 64x64 (4x4 grid of 16x16x32 MFMA)
#define BM 128
#define BN 128
#define BKE 64

typedef __attribute__((ext_vector_type(8))) short bf16x8;
typedef __attribute__((ext_vector_type(8))) unsigned short us8;
typedef __attribute__((ext_vector_type(4))) float f32x4;

__device__ __forceinline__ float sigf(float x) { return 1.0f / (1.0f + expf(-x)); }

__device__ __forceinline__ unsigned short f2bf(float f) {
    unsigned u = __float_as_uint(f);
    u += 0x7FFF + ((u >> 16) & 1);           // RNE
    return (unsigned short)(u >> 16);
}
__device__ __forceinline__ float bf2f(unsigned short h) {
    return __uint_as_float(((unsigned)h) << 16);
}

// ---- tiled-swizzled operand layout -------------------------------------------
// Matrix [R rows][Ks k] stored as 16 KB tiles of 128 rows x 64 k. Within a tile,
// granule (16 B = 8 elems) at position p = row*8 + (slot ^ (row&7)) holds logical
// k-granule `slot`. This is the LDS image the GEMM wants, so global_load_lds is
// an identity copy: lane address = tile_base + tid*16 B -> 1 KB contiguous/wave
// (R7's lane-scattered DMA fragmented into ~64 transactions/instr; this is the fix).
__device__ __forceinline__ size_t tidx(int n, int k, int KT) {
    return ((size_t)(n >> 7) * KT + (k >> 6)) * 8192
         + (size_t)(((n & 127) * 8 + (((k >> 3) & 7) ^ (n & 7))) * 8 + (k & 7));
}

// ---- one-shot weight convert: [W_iou^T|W_f^T] (2048xEPAD) + [U_iou^T|U_f^T]
// (2048xHDIM), both bf16 tiled-swizzled ----
__global__ __launch_bounds__(256) void wconv_all_k(
    const float* __restrict__ W_iou, const float* __restrict__ W_f,
    const float* __restrict__ U_iou, const float* __restrict__ U_f,
    unsigned short* __restrict__ Wt, unsigned short* __restrict__ Ut)
{
    const int SW = 2048 * EPAD;
    int t = blockIdx.x * 256 + threadIdx.x;
    if (t < SW) {
        int k = t % EPAD, n = t / EPAD;
        float v = 0.0f;
        if (k < EDIM)
            v = (n < 1536) ? W_iou[(size_t)k * 1536 + n] : W_f[(size_t)k * 512 + (n - 1536)];
        Wt[tidx(n, k, EPAD / 64)] = f2bf(v);
    } else {
        int u = t - SW;
        int k = u % HDIM, n = u / HDIM;
        float v = (n < 1536) ? U_iou[(size_t)k * 1536 + n] : U_f[(size_t)k * 512 + (n - 1536)];
        Ut[tidx(n, k, HDIM / 64)] = f2bf(v);
    }
}

// AF32=1: A rows gathered from fp32 embed (aidx), converted in-register,
//         ds_write into swizzled LDS (sources are normal coalesced loads).
// AF32=0: A is bf16 tiled-swizzled; DMA identity copy.
// EPI 0 : C = bf16(acc) ; EPI 1: C = bf16(acc*rowscale[row] + bias[col])
template <int AF32, int EPI>
__device__ __forceinline__ void gemm_body(
    const unsigned short* __restrict__ At,   // tiled bf16 A (AF32=0)
    const float* __restrict__ Af,            // f32 A (AF32=1)
    const int* __restrict__ aidx, const float* __restrict__ rowscale,
    const unsigned short* __restrict__ Bt,   // tiled bf16 B
    const float* __restrict__ b_iou, const float* __restrict__ b_f,
    unsigned short* __restrict__ C, int ldc, int Ks, int KA,
    int tile_m, int tile_n, unsigned short* smem)
{
    unsigned short* As = smem;               // [BM*BKE]
    unsigned short* Bs = smem + BM * BKE;

    const int tid  = threadIdx.x;
    const int wave = tid >> 6;
    const int lane = tid & 63;
    const int quad = lane >> 4;
    const int mcol = lane & 15;
    const int wm   = (wave >> 1) * 64;
    const int wn   = (wave & 1) * 64;
    const int KT   = Ks >> 6;

    // fp32-A gather prep: chunk c=tid+256j -> LDS granule c; fetch logical
    // k-granule (c&7)^(row&7) of gathered row (swizzled image built in-register)
    int agrow[4], kgo[4];
    if (AF32) {
#pragma unroll
        for (int j = 0; j < 4; ++j) {
            int c   = tid + 256 * j;
            int row = c >> 3;
            kgo[j]  = ((c & 7) ^ (row & 7)) * 8;
            agrow[j] = aidx[tile_m + row];
        }
    }

    const unsigned short* bbase0 = Bt + (size_t)((tile_n >> 7) * KT) * 8192;
    const unsigned short* abase0 = AF32 ? nullptr
        : At + (size_t)((tile_m >> 7) * KT) * 8192;

    f32x4 acc[4][4] = {};

    for (int kt = 0; kt < KT; ++kt) {
        // ---- stage A ----
        if (AF32) {
            const int k0 = kt * 64;
#pragma unroll
            for (int j = 0; j < 4; ++j) {
                const int e = k0 + kgo[j];
                float4 lo = make_float4(0.f, 0.f, 0.f, 0.f);
                float4 hi = make_float4(0.f, 0.f, 0.f, 0.f);
                const float* s = Af + (size_t)agrow[j] * KA + e;
                if (e + 4 <= KA) lo = *(const float4*)s;
                if (e + 8 <= KA) hi = *(const float4*)(s + 4);
                us8 o;
                o[0] = f2bf(lo.x); o[1] = f2bf(lo.y); o[2] = f2bf(lo.z); o[3] = f2bf(lo.w);
                o[4] = f2bf(hi.x); o[5] = f2bf(hi.y); o[6] = f2bf(hi.z); o[7] = f2bf(hi.w);
                *(us8*)(As + (size_t)(tid + 256 * j) * 8) = o;
            }
        } else {
            const unsigned short* abase = abase0 + (size_t)kt * 8192;
#pragma unroll
            for (int j = 0; j < 4; ++j) {
                __attribute__((address_space(3))) unsigned int* dA =
                    (__attribute__((address_space(3))) unsigned int*)(As + (wave * 64 + 256 * j) * 8);
                __builtin_amdgcn_global_load_lds(
                    (const __attribute__((address_space(1))) unsigned int*)
                        (abase + (size_t)(tid + 256 * j) * 8), dA, 16, 0, 0);
            }
        }
        // ---- stage B (tiled DMA, 1 KB contiguous per wave-instr) ----
        {
            const unsigned short* bbase = bbase0 + (size_t)kt * 8192;
#pragma unroll
            for (int j = 0; j < 4; ++j) {
                __attribute__((address_space(3))) unsigned int* dB =
                    (__attribute__((address_space(3))) unsigned int*)(Bs + (wave * 64 + 256 * j) * 8);
                __builtin_amdgcn_global_load_lds(
                    (const __attribute__((address_space(1))) unsigned int*)
                        (bbase + (size_t)(tid + 256 * j) * 8), dB, 16, 0, 0);
            }
        }
        __syncthreads();

#pragma unroll
        for (int kh = 0; kh < 2; ++kh) {
            bf16x8 afr[4], bfr[4];
#pragma unroll
            for (int mt = 0; mt < 4; ++mt) {
                int rw = wm + mt * 16 + mcol;
                int p  = (kh * 4 + quad) ^ (rw & 7);
                afr[mt] = *(const bf16x8*)(As + (rw * 8 + p) * 8);
            }
#pragma unroll
            for (int nt = 0; nt < 4; ++nt) {
                int rw = wn + nt * 16 + mcol;
                int p  = (kh * 4 + quad) ^ (rw & 7);
                bfr[nt] = *(const bf16x8*)(Bs + (rw * 8 + p) * 8);
            }
#pragma unroll
            for (int mt = 0; mt < 4; ++mt)
#pragma unroll
                for (int nt = 0; nt < 4; ++nt)
                    acc[mt][nt] = __builtin_amdgcn_mfma_f32_16x16x32_bf16(
                        afr[mt], bfr[nt], acc[mt][nt], 0, 0, 0);
        }
        __syncthreads();
    }

    // ---- epilogue: bf16 C-tile via LDS (XOR swizzle), 128 B/thread stores ----
    unsigned short* Ct = smem;   // 32 KB = 128*128 ushort
#pragma unroll
    for (int mt = 0; mt < 4; ++mt) {
        const int rl = wm + mt * 16 + quad * 4;
        float4 ts = make_float4(1.f, 1.f, 1.f, 1.f);
        if (EPI == 1) ts = *(const float4*)&rowscale[tile_m + rl];
        const float tsv[4] = {ts.x, ts.y, ts.z, ts.w};
#pragma unroll
        for (int nt = 0; nt < 4; ++nt) {
            const int cl = wn + nt * 16 + mcol;
            float bv = 0.0f;
            if (EPI == 1) {
                int col = tile_n + cl;
                bv = (col < 3 * HDIM) ? b_iou[col] : b_f[col - 3 * HDIM];
            }
#pragma unroll
            for (int r = 0; r < 4; ++r) {
                int row = rl + r;
                int g   = (cl >> 3) ^ (row & 7);
                float v = acc[mt][nt][r];
                if (EPI == 1) v = v * tsv[r] + bv;
                Ct[row * BN + g * 8 + (cl & 7)] = f2bf(v);
            }
        }
    }
    __syncthreads();
    {
        const int row  = tid >> 1;
        const int half = tid & 1;
        unsigned short* gp = C + (size_t)(tile_m + row) * ldc + tile_n + half * 64;
#pragma unroll
        for (int v = 0; v < 8; ++v) {
            int g  = half * 8 + v;
            int gs = g ^ (row & 7);
            *(us8*)(gp + v * 8) = *(const us8*)(Ct + row * BN + gs * 8);
        }
    }
}

// Fused per-level GEMM dispatch. LEAF: W only (12 N-tiles, iou cols).
// Else: even blocks = Z (h_prev@[U_iou|U_f]), odd = W (embed-gather@[W_iou|W_f]).
// Same-M blocks have linear-id stride 64/128 (both % 8 == 0) -> one XCD, so
// shared-A re-reads stay L2-local (R6-verified heuristic).
template <bool LEAF>
__global__ __launch_bounds__(256) void mgemm_fused_k(
    const float* __restrict__ Af, const int* __restrict__ aidx,
    const float* __restrict__ rowscale,
    const unsigned short* __restrict__ Wt,
    const float* __restrict__ b_iou, const float* __restrict__ b_f,
    unsigned short* __restrict__ Cw,
    const unsigned short* __restrict__ At,   // tiled hb_prev
    const unsigned short* __restrict__ Ut,
    unsigned short* __restrict__ Cz)
{
    __shared__ __align__(16) unsigned short smem[2 * BM * BKE];  // 32 KB
    const int bid = blockIdx.x;
    if (LEAF) {
        int m = bid & 63, n = bid >> 6;
        gemm_body<1, 1>(nullptr, Af, aidx, rowscale, Wt, b_iou, b_f,
                        Cw, 4 * HDIM, EPAD, EDIM, m * BM, n * BN, smem);
    } else {
        int g = bid & 1, t = bid >> 1;
        int m = t & 63, n = t >> 6;
        if (g) gemm_body<1, 1>(nullptr, Af, aidx, rowscale, Wt, b_iou, b_f,
                               Cw, 4 * HDIM, EPAD, EDIM, m * BM, n * BN, smem);
        else   gemm_body<0, 0>(At, nullptr, nullptr, nullptr, Ut, nullptr, nullptr,
                               Cz, 4 * HDIM, HDIM, HDIM, m * BM, n * BN, smem);
    }
}

// fused child-sum + fc + gates (non-leaf).
// ioux row: bf16 [i|o|u|xwf+bf] (2048, row-major). Z row: bf16 [hU_iou|hU_f].
//   ia = i + sum_k m_k*Zi[c_k] ; fc = sum_k sigf(xw + m_k*Zf[c_k])*m_k*c_prev[c_k]
//   c = sigf(ia)*tanh(ua) + fc ; h = sigf(oa)*tanh(c)
// hb_new written in tiled-swizzled layout (consumed only by next Z-GEMM DMA).
template <bool LAST>
__global__ __launch_bounds__(256) void gatefc_k(
    const unsigned short* __restrict__ ioux, const unsigned short* __restrict__ Z,
    const int* __restrict__ cidx, const float* __restrict__ cmask,
    const float* __restrict__ c_prev,
    float* __restrict__ c_new, unsigned short* __restrict__ hb_new,
    float* __restrict__ h_out)
{
    int t  = blockIdx.x * 256 + threadIdx.x;   // NN*HDIM/8 threads
    int n  = t >> 6;
    int j8 = (t & 63) << 3;
    const unsigned short* xr = ioux + (size_t)n * 4 * HDIM + j8;
    us8 xi = *(const us8*)xr;
    us8 xo = *(const us8*)(xr + HDIM);
    us8 xu = *(const us8*)(xr + 2 * HDIM);
    us8 xf = *(const us8*)(xr + 3 * HDIM);
    float ia[8], oa[8], ua[8], xw[8], fc[8];
#pragma unroll
    for (int j = 0; j < 8; ++j) {
        ia[j] = bf2f(xi[j]); oa[j] = bf2f(xo[j]);
        ua[j] = bf2f(xu[j]); xw[j] = bf2f(xf[j]);
        fc[j] = 0.0f;
    }
    int4   ci = *(const int4*)&cidx[n * KCH];
    float4 cm = *(const float4*)&cmask[n * KCH];
    const int   cia[4] = {ci.x, ci.y, ci.z, ci.w};
    const float cma[4] = {cm.x, cm.y, cm.z, cm.w};
#pragma unroll
    for (int k = 0; k < KCH; ++k) {
        const float m = cma[k];
        const unsigned short* zr = Z + (size_t)cia[k] * 4 * HDIM + j8;
        us8 zi = *(const us8*)zr;
        us8 zo = *(const us8*)(zr + HDIM);
        us8 zu = *(const us8*)(zr + 2 * HDIM);
        us8 zf = *(const us8*)(zr + 3 * HDIM);
        const float* cpr = c_prev + (size_t)cia[k] * HDIM + j8;
        float4 ca = *(const float4*)cpr;
        float4 cb = *(const float4*)(cpr + 4);
        const float cp[8] = {ca.x, ca.y, ca.z, ca.w, cb.x, cb.y, cb.z, cb.w};
#pragma unroll
        for (int j = 0; j < 8; ++j) {
            ia[j] += m * bf2f(zi[j]);
            oa[j] += m * bf2f(zo[j]);
            ua[j] += m * bf2f(zu[j]);
            fc[j] += sigf(xw[j] + m * bf2f(zf[j])) * m * cp[j];
        }
    }
    float cv[8], hv[8];
#pragma unroll
    for (int j = 0; j < 8; ++j) {
        cv[j] = sigf(ia[j]) * tanhf(ua[j]) + fc[j];
        hv[j] = sigf(oa[j]) * tanhf(cv[j]);
    }
    if (LAST) {
        *(float4*)(h_out + (size_t)n * HDIM + j8)     = make_float4(hv[0], hv[1], hv[2], hv[3]);
        *(float4*)(h_out + (size_t)n * HDIM + j8 + 4) = make_float4(hv[4], hv[5], hv[6], hv[7]);
    } else {
        *(float4*)(c_new + (size_t)n * HDIM + j8)     = make_float4(cv[0], cv[1], cv[2], cv[3]);
        *(float4*)(c_new + (size_t)n * HDIM + j8 + 4) = make_float4(cv[4], cv[5], cv[6], cv[7]);
        us8 hb;
#pragma unroll
        for (int j = 0; j < 8; ++j) hb[j] = f2bf(hv[j]);
        size_t ho = ((size_t)(n >> 7) * 8 + (j8 >> 6)) * 8192
                  + (size_t)(((n & 127) * 8 + (((j8 >> 3) & 7) ^ (n & 7))) * 8);
        *(us8*)(hb_new + ho) = hb;
    }
}

// leaf: fc = 0, no children (reads only i|o|u cols of ioux)
__global__ __launch_bounds__(256) void gateleaf_k(
    const unsigned short* __restrict__ ioux,
    float* __restrict__ c_new, unsigned short* __restrict__ hb_new)
{
    int t  = blockIdx.x * 256 + threadIdx.x;
    int n  = t >> 6;
    int j8 = (t & 63) << 3;
    const unsigned short* xr = ioux + (size_t)n * 4 * HDIM + j8;
    us8 xi = *(const us8*)xr;
    us8 xo = *(const us8*)(xr + HDIM);
    us8 xu = *(const us8*)(xr + 2 * HDIM);
    float cv[8], hv[8];
#pragma unroll
    for (int j = 0; j < 8; ++j) {
        cv[j] = sigf(bf2f(xi[j])) * tanhf(bf2f(xu[j]));
        hv[j] = sigf(bf2f(xo[j])) * tanhf(cv[j]);
    }
    *(float4*)(c_new + (size_t)n * HDIM + j8)     = make_float4(cv[0], cv[1], cv[2], cv[3]);
    *(float4*)(c_new + (size_t)n * HDIM + j8 + 4) = make_float4(cv[4], cv[5], cv[6], cv[7]);
    us8 hb;
#pragma unroll
    for (int j = 0; j < 8; ++j) hb[j] = f2bf(hv[j]);
    size_t ho = ((size_t)(n >> 7) * 8 + (j8 >> 6)) * 8192
              + (size_t)(((n & 127) * 8 + (((j8 >> 3) & 7) ^ (n & 7))) * 8);
    *(us8*)(hb_new + ho) = hb;
}

extern "C" void kernel_launch(void* const* d_in, const int* in_sizes, int n_in,
                              void* d_out, int out_size, void* d_ws, size_t ws_size,
                              hipStream_t stream)
{
    const int*   vocab_ix   = (const int*)d_in[0];     // [L,N]
    const int*   child_idx  = (const int*)d_in[1];     // [L,N,K]
    const float* token_mask = (const float*)d_in[2];   // [L,N]
    const float* child_mask = (const float*)d_in[3];   // [L,N,K]
    const float* embed      = (const float*)d_in[4];   // [V,E] f32
    const float* W_iou      = (const float*)d_in[5];   // [E,3H]
    const float* U_iou      = (const float*)d_in[6];   // [H,3H]
    const float* b_iou      = (const float*)d_in[7];   // [3H]
    const float* W_f        = (const float*)d_in[8];   // [E,H]
    const float* U_f        = (const float*)d_in[9];   // [H,H]
    const float* b_f        = (const float*)d_in[10];  // [H]
    float* out = (float*)d_out;                        // [N,H] level-0 h

    // ---- workspace (~121 MB live < 256 MB L3) ----
    float* ws = (float*)d_ws;
    float* c0 = ws;                                    // [N,H] f32
    float* c1 = c0 + (size_t)NN * HDIM;                // [N,H] f32
    unsigned short* usb   = (unsigned short*)(c1 + (size_t)NN * HDIM);
    unsigned short* hb0   = usb;                                // [N,H] bf16 tiled
    unsigned short* hb1   = hb0 + (size_t)NN * HDIM;            // [N,H] bf16 tiled
    unsigned short* ioux  = hb1 + (size_t)NN * HDIM;            // [N,4H] bf16 rm
    unsigned short* Z     = ioux + (size_t)NN * 4 * HDIM;       // [N,4H] bf16 rm
    unsigned short* Wt    = Z + (size_t)NN * 4 * HDIM;          // [2048,EPAD] tiled
    unsigned short* Ut    = Wt + (size_t)4 * HDIM * EPAD;       // [2048,HDIM] tiled

    dim3 blk(256);

    // weight converts, single dispatch (2048*320 + 2048*512 = 1703936 elems)
    wconv_all_k<<<dim3((2048 * EPAD + 2048 * HDIM) / 256), blk, 0, stream>>>(
        W_iou, W_f, U_iou, U_f, Wt, Ut);

    unsigned short* bbuf[2] = { hb0, hb1 };
    float*          cbuf[2] = { c0,  c1  };

    const int ew_blocks = NN * HDIM / 8 / 256;   // 2048

    for (int l = LVLS - 1; l >= 0; --l) {
        const int p = (LVLS - 1 - l);
        unsigned short* hb_new  = bbuf[p & 1];
        float*          c_new   = cbuf[p & 1];
        unsigned short* hb_prev = bbuf[(p & 1) ^ 1];
        float*          c_prev  = cbuf[(p & 1) ^ 1];
        const int*   cix = child_idx  + (size_t)l * NN * KCH;
        const float* cm  = child_mask + (size_t)l * NN * KCH;
        const int*   vix = vocab_ix   + (size_t)l * NN;
        const float* tm  = token_mask + (size_t)l * NN;
        const bool leaf = (l == LVLS - 1);

        if (leaf) {
            // W only: ioux[:, :1536] = (embed[vix]*tm)@W_iou + b_iou
            mgemm_fused_k<true><<<dim3(64 * 12), blk, 0, stream>>>(
                embed, vix, tm, Wt, b_iou, b_f, ioux, nullptr, nullptr, nullptr);
            gateleaf_k<<<dim3(ew_blocks), blk, 0, stream>>>(ioux, c_new, hb_new);
        } else {
            // fused: Z = hb_prev@[U_iou|U_f]  +  ioux = (embed[vix]*tm)@[W_iou|W_f]+bias
            mgemm_fused_k<false><<<dim3(2 * 64 * 16), blk, 0, stream>>>(
                embed, vix, tm, Wt, b_iou, b_f, ioux, hb_prev, Ut, Z);

            if (l == 0) {
                gatefc_k<true><<<dim3(ew_blocks), blk, 0, stream>>>(
                    ioux, Z, cix, cm, c_prev, nullptr, nullptr, out);
            } else {
                gatefc_k<false><<<dim3(ew_blocks), blk, 0, stream>>>(
                    ioux, Z, cix, cm, c_prev, c_new, hb_new, nullptr);
            }
        }
    }
}